// Round 5
// baseline (725.709 us; speedup 1.0000x reference)
//
#include <hip/hip_runtime.h>
#include <hip/hip_fp16.h>

typedef _Float16 f16;
typedef _Float16 f16x2 __attribute__((ext_vector_type(2)));
typedef _Float16 f16x8 __attribute__((ext_vector_type(8)));
typedef float    f32x4 __attribute__((ext_vector_type(4)));

#define NB   8192
#define TOUT 10
#define LMAX 12
#define EMB  300

__device__ __forceinline__ float sigm_(float x) {
    return __builtin_amdgcn_rcpf(1.0f + __builtin_amdgcn_exp2f(x * -1.44269504f));
}
__device__ __forceinline__ float tanh_(float x) {
    return 1.0f - 2.0f * __builtin_amdgcn_rcpf(1.0f + __builtin_amdgcn_exp2f(x * 2.88539008f));
}

// async global->LDS, 16B per lane. LDS dest is wave-uniform base + lane*16.
__device__ __forceinline__ void gl_lds16(const f16* g, f16* l) {
    __builtin_amdgcn_global_load_lds(
        (const __attribute__((address_space(1))) void*)g,
        (__attribute__((address_space(3))) void*)l, 16, 0, 0);
}

#define WAITV(n) asm volatile("s_waitcnt vmcnt(" #n ")" ::: "memory")

// ---------------------------------------------------------------------------
// K0a: pack LSTM weights into MFMA B-fragment tiles, f16, gate-permuted cols.
// Dest per dir: [kc 0..15][ntile 0..63][512 f16]; within tile element (k,n):
// offset = ((k%32)/8*16 + n%16)*8 + k%8 (lane l reads l*8..l*8+7).
// 16-wave / 64-col-per-wave permutation:
//   n -> gate = (n>>4)&3, unit u = ((n>>6)<<4) | (n&15)
// wave's 4 n-tiles (ntile = wave*4+gate) are the 4 gates of units
// [wave*16, wave*16+16); lane l16 owns unit wave*16+l16.
// ---------------------------------------------------------------------------
__global__ __launch_bounds__(256) void pack_w2(
    const float* __restrict__ wih_f, const float* __restrict__ whh_f,
    const float* __restrict__ wih_b, const float* __restrict__ whh_b,
    f16* __restrict__ Wp) {
    int idx = blockIdx.x * 256 + threadIdx.x;   // 0 .. 2*524288-1
    int d   = idx >> 19;
    int r   = idx & 524287;
    int tile = r >> 9;
    int e    = r & 511;
    int kc = tile >> 6, nt = tile & 63;
    int khi = e >> 7, rem = e & 127, nl = rem >> 3, klo = rem & 7;
    int n = nt * 16 + nl;
    int k = kc * 32 + khi * 8 + klo;
    int gate = (n >> 4) & 3;
    int u = ((n >> 6) << 4) | (n & 15);
    int srow = gate * 256 + u;
    const float* wih = d ? wih_b : wih_f;
    const float* whh = d ? whh_b : whh_f;
    float v = (k < 256) ? wih[srow * 256 + k] : whh[srow * 256 + (k - 256)];
    Wp[idx] = (f16)v;
}

__global__ __launch_bounds__(256) void pack_bias(
    const float* __restrict__ bih_f, const float* __restrict__ bhh_f,
    const float* __restrict__ bih_b, const float* __restrict__ bhh_b,
    float* __restrict__ bp) {
    int idx = blockIdx.x * 256 + threadIdx.x;   // 2048
    int d = idx >> 10, n = idx & 1023;
    int gate = (n >> 4) & 3;
    int u = ((n >> 6) << 4) | (n & 15);
    int srow = gate * 256 + u;
    bp[idx] = d ? (bih_b[srow] + bhh_b[srow]) : (bih_f[srow] + bhh_f[srow]);
}

// K0b: pack out_w (512x512) into B-fragment tiles: [kc 0..15][ntile 0..31][512]
__global__ __launch_bounds__(256) void pack_w3(
    const float* __restrict__ out_w, f16* __restrict__ W3p) {
    int idx = blockIdx.x * 256 + threadIdx.x;   // 262144
    int tile = idx >> 9, e = idx & 511;
    int kc = tile >> 5, nt = tile & 31;
    int khi = e >> 7, rem = e & 127, nl = rem >> 3, klo = rem & 7;
    int n = nt * 16 + nl, k = kc * 32 + khi * 8 + klo;
    W3p[idx] = (f16)out_w[n * 512 + k];
}

// K0c: P[36][256] = emb_table @ enc_w^T + enc_b (fp32)
__global__ __launch_bounds__(256) void enc_proj(
    const float* __restrict__ tab, const float* __restrict__ ew,
    const float* __restrict__ eb, float* __restrict__ P) {
    int v = blockIdx.x, j = threadIdx.x;
    const float* a = tab + v * EMB;
    const float* w = ew + j * EMB;
    float s = 0.0f;
    for (int k = 0; k < EMB; ++k) s += a[k] * w[k];
    P[v * 256 + j] = s + eb[j];
}

// ---------------------------------------------------------------------------
// K1: build seq in MFMA A-fragment tile layout, f16.
// seqp: [t 0..9][mtile 0..511][kc 0..7][512 f16]; element (row,k):
// offset = ((k%32)/8*16 + row%16)*8 + k%8
// ---------------------------------------------------------------------------
__global__ __launch_bounds__(256) void build_seq(
    const int* __restrict__ words, const int* __restrict__ lengths,
    const float* __restrict__ P, f16* __restrict__ seqp) {
    int gi = blockIdx.x * 256 + threadIdx.x;    // 2,621,440 total
    int bl  = gi & 15;
    int khi = (gi >> 4) & 3;
    int kc  = (gi >> 6) & 7;
    int mt  = (gi >> 9) & 511;
    int t   = gi >> 18;
    int b = mt * 16 + bl;
    int L = lengths[b];
    float pos = ((float)t * (float)(L - 1)) / 9.0f;
    int i0 = (int)pos;
    float f = pos - (float)i0;
    int i1 = min(i0 + 1, L - 1);
    int c0 = words[b * LMAX + i0];
    int c1 = words[b * LMAX + i1];
    const float* p0 = P + c0 * 256 + kc * 32 + khi * 8;
    const float* p1 = P + c1 * 256 + kc * 32 + khi * 8;
    f16x8 r;
#pragma unroll
    for (int j = 0; j < 8; ++j) {
        float v = p0[j] * (1.0f - f) + p1[j] * f;
        v = fmaxf(v, 0.0f);
        r[j] = (f16)v;
    }
    *((f16x8*)seqp + gi) = r;
}

// ---------------------------------------------------------------------------
// K2: fused BiLSTM. 256 blocks x 1024 thr (16 waves), 1 block/CU, 4 w/SIMD.
// Round-5: the weight stream is pipelined through the LDS-DMA queue at
// HALF-kc granularity (32 phases/step; per wave per phase: 2 x
// global_load_lds of 1KB tiles into a private 2KB slot of a 2-slot dbuf),
// with HAND-COUNTED vmcnt waits (WAITV(2) all phases, WAITV(0) at p31 --
// table verified by FIFO simulation incl. the mid-step seq DMA). This is
// register-pressure-free prefetch: the compiler cannot sink it (round-4
// failure) and the cover per wait is 2 phases (~1200 cy) >> L2 latency
// (round-3 failure was 84 cy cover + seq at FIFO head).
// LDS 128 KB: wbuf[2][16K] 64K + hbuf single 32K + sbuf single 32K.
// Single h buffer: raw s_barrier (no vmcnt drain) separates last h-read
// from combine-write. Single seq buffer: raw s_barrier after the seq-half
// phases, then seq(t+1) DMA. Combine writes h ONLY to LDS; h(t-1) is
// copied to hcat as COALESCED f16x8 stores (kills the write-allocate RMW
// that inflated FETCH_SIZE to 114-126 MB in rounds 2-4).
// ---------------------------------------------------------------------------
__global__ __launch_bounds__(1024) void lstm_fused(
    const f16* __restrict__ seqp, const f16* __restrict__ Wp,
    const float* __restrict__ bp, f16* __restrict__ hcat) {
    const int dir  = blockIdx.x >> 7;
    const int r0t  = (blockIdx.x & 127) << 2;   // row-tile base, 4 tiles of 16
    const int wave = threadIdx.x >> 6;          // 0..15
    const int lane = threadIdx.x & 63;
    const int l16  = lane & 15;
    const int quad = lane >> 4;

    __shared__ __align__(16) f16 hbuf[16384];       // 32 KB h state (single)
    __shared__ __align__(16) f16 sbuf[16384];       // 32 KB seq tile (single)
    __shared__ __align__(16) f16 wbuf[2][16384];    // 64 KB weight dbuf

    // zero h0
    {
        f16x8 z = {(f16)0, (f16)0, (f16)0, (f16)0, (f16)0, (f16)0, (f16)0, (f16)0};
        for (int i = threadIdx.x; i < 2048; i += 1024) ((f16x8*)hbuf)[i] = z;
    }
    // stage seq tile for t0
    {
        const int t0 = dir ? 9 : 0;
        const f16* s0 = seqp + (size_t)(t0 * 512 + r0t) * 4096;
        gl_lds16(s0 + threadIdx.x * 8,        &sbuf[wave * 512]);
        gl_lds16(s0 + 8192 + threadIdx.x * 8, &sbuf[8192 + wave * 512]);
    }

    // per-lane gate biases: wave owns cols [wave*64, wave*64+64); nt = gate
    const float* bpd = bp + dir * 1024 + wave * 64;
    float bias_l[4];
#pragma unroll
    for (int nt = 0; nt < 4; ++nt) bias_l[nt] = bpd[nt * 16 + l16];

    // weight tile (kc, nt): Wsl + (kc*64 + nt)*512   (wave, lane folded in)
    const f16* Wsl = Wp + dir * 524288 + wave * 2048 + lane * 8;
    f16*       wds = &wbuf[0][wave * 1024];              // slot0 dest (uniform)
    const f16* wbr = &wbuf[0][wave * 1024 + lane * 8];   // slot0 read (lane)

    const f16* sbl = sbuf + lane * 8;
    const f16* hbl = hbuf + lane * 8;

    // combine geometry: lane owns h-unit u = wave*16 + l16
    const int slot = wave >> 1;
    const int ofs0 = (((wave & 1) * 2 + (l16 >> 3)) * 16 + quad * 4) * 8 + (l16 & 7);

    float cst[4][4];
#pragma unroll
    for (int m = 0; m < 4; ++m)
#pragma unroll
        for (int q = 0; q < 4; ++q) cst[m][q] = 0.0f;

    // weight prologue: phases 0 (kc0 nt0,1 -> slot0) and 1 (kc0 nt2,3 -> slot1)
    gl_lds16(Wsl + 0 * 512, wds);
    gl_lds16(Wsl + 1 * 512, wds + 512);
    gl_lds16(Wsl + 2 * 512, wds + 16384);
    gl_lds16(Wsl + 3 * 512, wds + 16384 + 512);

    __syncthreads();   // drains h0-zero, seq t0, weight prologue

// phase P (0..31): kc = P>>1, half = P&1 (nt pair = half*2+{0,1});
// consume wbuf slot (P&1); after MFMA, issue DMA for phase P+2 (same slot).
#define PHASE(P)  do {                                                         \
    if ((P) == 31) { WAITV(0); } else { WAITV(2); }                            \
    const f16* br_ = wbr + ((P) & 1) * 16384;                                  \
    f16x8 b0_ = *(const f16x8*)(br_);                                          \
    f16x8 b1_ = *(const f16x8*)(br_ + 512);                                    \
    if (((P) & 1) == 0) {                                                      \
        const f16* ab_ = (((P) >> 1) < 8) ? sbl : hbl;                         \
        const int ko_ = ((P) >> 1) & 7;                                        \
        af0 = *(const f16x8*)(ab_ + (0 * 8 + ko_) * 512);                      \
        af1 = *(const f16x8*)(ab_ + (1 * 8 + ko_) * 512);                      \
        af2 = *(const f16x8*)(ab_ + (2 * 8 + ko_) * 512);                      \
        af3 = *(const f16x8*)(ab_ + (3 * 8 + ko_) * 512);                      \
    }                                                                          \
    __builtin_amdgcn_s_setprio(1);                                             \
    acc[0][((P)&1)*2]   = __builtin_amdgcn_mfma_f32_16x16x32_f16(af0, b0_, acc[0][((P)&1)*2],   0,0,0); \
    acc[1][((P)&1)*2]   = __builtin_amdgcn_mfma_f32_16x16x32_f16(af1, b0_, acc[1][((P)&1)*2],   0,0,0); \
    acc[2][((P)&1)*2]   = __builtin_amdgcn_mfma_f32_16x16x32_f16(af2, b0_, acc[2][((P)&1)*2],   0,0,0); \
    acc[3][((P)&1)*2]   = __builtin_amdgcn_mfma_f32_16x16x32_f16(af3, b0_, acc[3][((P)&1)*2],   0,0,0); \
    acc[0][((P)&1)*2+1] = __builtin_amdgcn_mfma_f32_16x16x32_f16(af0, b1_, acc[0][((P)&1)*2+1], 0,0,0); \
    acc[1][((P)&1)*2+1] = __builtin_amdgcn_mfma_f32_16x16x32_f16(af1, b1_, acc[1][((P)&1)*2+1], 0,0,0); \
    acc[2][((P)&1)*2+1] = __builtin_amdgcn_mfma_f32_16x16x32_f16(af2, b1_, acc[2][((P)&1)*2+1], 0,0,0); \
    acc[3][((P)&1)*2+1] = __builtin_amdgcn_mfma_f32_16x16x32_f16(af3, b1_, acc[3][((P)&1)*2+1], 0,0,0); \
    __builtin_amdgcn_s_setprio(0);                                             \
    if ((P) < 30) {                                                            \
        f16* wd_ = wds + ((P) & 1) * 16384;                                    \
        gl_lds16(Wsl + ((((P) + 2) >> 1) * 64 + (((P) + 2) & 1) * 2) * 512,       wd_);       \
        gl_lds16(Wsl + ((((P) + 2) >> 1) * 64 + (((P) + 2) & 1) * 2 + 1) * 512,   wd_ + 512); \
    }                                                                          \
} while (0)

    int step = 0;
#pragma unroll 1
    for (; step < TOUT; ++step) {
        const int t = dir ? (9 - step) : step;

        f32x4 acc[4][4];
#pragma unroll
        for (int m = 0; m < 4; ++m)
#pragma unroll
            for (int nt = 0; nt < 4; ++nt)
#pragma unroll
                for (int q = 0; q < 4; ++q) acc[m][nt][q] = bias_l[nt];

        f16x8 af0, af1, af2, af3;

        // seq-half: kc 0..7 (phases 0..15)
        PHASE(0);  PHASE(1);  PHASE(2);  PHASE(3);
        PHASE(4);  PHASE(5);  PHASE(6);  PHASE(7);
        PHASE(8);  PHASE(9);  PHASE(10); PHASE(11);
        PHASE(12); PHASE(13); PHASE(14); PHASE(15);

        // all waves done reading sbuf -> safe to overwrite (raw barrier:
        // no vmcnt drain, weight pipeline stays in flight)
        __builtin_amdgcn_s_barrier();
        if (step != 9) {
            const int tn = dir ? (t - 1) : (t + 1);
            const f16* ns = seqp + (size_t)(tn * 512 + r0t) * 4096;
            gl_lds16(ns + threadIdx.x * 8,        &sbuf[wave * 512]);
            gl_lds16(ns + 8192 + threadIdx.x * 8, &sbuf[8192 + wave * 512]);
        }

        // h-half: kc 8..15 (phases 16..31)
        PHASE(16); PHASE(17); PHASE(18); PHASE(19);
        PHASE(20); PHASE(21); PHASE(22); PHASE(23);
        PHASE(24); PHASE(25); PHASE(26); PHASE(27);
        PHASE(28); PHASE(29); PHASE(30); PHASE(31);

        // deferred COALESCED copy h(t-1) -> hcat (reads hbuf before barrier B;
        // stores sit at FIFO tail, drained by the step-end barrier)
        if (step != 0) {
            const int tp = dir ? (t + 1) : (t - 1);
#pragma unroll
            for (int e0 = 0; e0 < 2; ++e0) {
                const int e = (int)threadIdx.x + e0 * 1024;
                f16x8 v = ((const f16x8*)hbuf)[e];
                ((f16x8*)hcat)[((size_t)(tp * 512 + r0t + (e >> 9)) * 16 + dir * 8) * 64 + (e & 511)] = v;
            }
        }
        // next-step weight prologue (own slots already consumed)
        if (step != 9) {
            gl_lds16(Wsl + 0 * 512, wds);
            gl_lds16(Wsl + 1 * 512, wds + 512);
            gl_lds16(Wsl + 2 * 512, wds + 16384);
            gl_lds16(Wsl + 3 * 512, wds + 16384 + 512);
        }

        // all waves done reading h(t-1) -> safe to write h(t) (raw barrier)
        __builtin_amdgcn_s_barrier();

        // lane-local gate combine; h -> LDS only.
        // acc[m][nt][q]: row = m*16 + quad*4 + q, gate = nt, unit = wave*16+l16
#pragma unroll
        for (int m = 0; m < 4; ++m) {
#pragma unroll
            for (int q = 0; q < 4; ++q) {
                float iv = acc[m][0][q];
                float fv = acc[m][1][q];
                float gv = acc[m][2][q];
                float ov = acc[m][3][q];
                float c = sigm_(fv) * cst[m][q] + sigm_(iv) * tanh_(gv);
                cst[m][q] = c;
                hbuf[(m * 8 + slot) * 512 + ofs0 + q * 8] = (f16)(sigm_(ov) * tanh_(c));
            }
        }

        __syncthreads();   // full barrier: h visible, seq DMA + stores drained
    }
#undef PHASE

    // epilogue: copy h(t_last) -> hcat
    {
        const int tl = dir ? 0 : 9;
#pragma unroll
        for (int e0 = 0; e0 < 2; ++e0) {
            const int e = (int)threadIdx.x + e0 * 1024;
            f16x8 v = ((const f16x8*)hbuf)[e];
            ((f16x8*)hcat)[((size_t)(tl * 512 + r0t + (e >> 9)) * 16 + dir * 8) * 64 + (e & 511)] = v;
        }
    }
}

// ---------------------------------------------------------------------------
// K3: out = h_cat(81920x512 f16, frag layout) @ W3p + out_b -> fp32 (B,10,512)
// 1280 blocks x 512 thr; block tile 64 rows x 512 cols; wave: 64x64.
// ---------------------------------------------------------------------------
__global__ __launch_bounds__(512) void out_gemm(
    const f16* __restrict__ hcat, const f16* __restrict__ W3p,
    const float* __restrict__ out_b, float* __restrict__ out) {
    const int mt0  = blockIdx.x << 2;
    const int wave = threadIdx.x >> 6;
    const int lane = threadIdx.x & 63;
    const int l16  = lane & 15;
    const int quad = lane >> 4;
    const int n0   = wave * 64;

    float bias_l[4];
#pragma unroll
    for (int nt = 0; nt < 4; ++nt) bias_l[nt] = out_b[n0 + nt * 16 + l16];

    f32x4 acc[4][4];
#pragma unroll
    for (int m = 0; m < 4; ++m)
#pragma unroll
        for (int nt = 0; nt < 4; ++nt)
#pragma unroll
            for (int q = 0; q < 4; ++q) acc[m][nt][q] = bias_l[nt];

#pragma unroll 2
    for (int kc = 0; kc < 16; ++kc) {
        f16x8 a[4], b[4];
#pragma unroll
        for (int m = 0; m < 4; ++m)
            a[m] = *(const f16x8*)(hcat + ((size_t)((mt0 + m) * 16 + kc) * 512 + lane * 8));
#pragma unroll
        for (int nt = 0; nt < 4; ++nt)
            b[nt] = *(const f16x8*)(W3p + ((kc * 32 + wave * 4 + nt) * 512 + lane * 8));
#pragma unroll
        for (int m = 0; m < 4; ++m)
#pragma unroll
            for (int nt = 0; nt < 4; ++nt)
                acc[m][nt] = __builtin_amdgcn_mfma_f32_16x16x32_f16(a[m], b[nt], acc[m][nt], 0, 0, 0);
    }

#pragma unroll
    for (int m = 0; m < 4; ++m) {
#pragma unroll
        for (int nt = 0; nt < 4; ++nt) {
#pragma unroll
            for (int q = 0; q < 4; ++q) {
                int R = mt0 * 16 + m * 16 + quad * 4 + q;
                int t = R >> 13;
                int b = R & 8191;
                out[(size_t)(b * 10 + t) * 512 + n0 + nt * 16 + l16] = acc[m][nt][q];
            }
        }
    }
}

// ---------------------------------------------------------------------------
extern "C" void kernel_launch(void* const* d_in, const int* in_sizes, int n_in,
                              void* d_out, int out_size, void* d_ws, size_t ws_size,
                              hipStream_t stream) {
    const int*   words   = (const int*)d_in[0];
    const int*   lengths = (const int*)d_in[1];
    const float* tab     = (const float*)d_in[2];
    const float* enc_w   = (const float*)d_in[3];
    const float* enc_b   = (const float*)d_in[4];
    const float* wih_f   = (const float*)d_in[5];
    const float* whh_f   = (const float*)d_in[6];
    const float* bih_f   = (const float*)d_in[7];
    const float* bhh_f   = (const float*)d_in[8];
    const float* wih_b   = (const float*)d_in[9];
    const float* whh_b   = (const float*)d_in[10];
    const float* bih_b   = (const float*)d_in[11];
    const float* bhh_b   = (const float*)d_in[12];
    const float* out_w   = (const float*)d_in[13];
    const float* out_b   = (const float*)d_in[14];
    float* out = (float*)d_out;

    char* ws = (char*)d_ws;
    f16*   Wp   = (f16*)(ws + 0);           //  2 MB
    f16*   W3p  = (f16*)(ws + 2097152);     //  0.5 MB
    float* bp   = (float*)(ws + 2621440);   //  8 KB
    float* P    = (float*)(ws + 2629632);   //  36 KB
    f16*   seqp = (f16*)(ws + 2666496);     //  40 MB
    f16*   hcat = (f16*)(ws + 44609536);    //  80 MB  (total ~122.6 MB)

    pack_w2<<<4096, 256, 0, stream>>>(wih_f, whh_f, wih_b, whh_b, Wp);
    pack_bias<<<8, 256, 0, stream>>>(bih_f, bhh_f, bih_b, bhh_b, bp);
    pack_w3<<<1024, 256, 0, stream>>>(out_w, W3p);
    enc_proj<<<36, 256, 0, stream>>>(tab, enc_w, enc_b, P);
    build_seq<<<10240, 256, 0, stream>>>(words, lengths, P, seqp);
    lstm_fused<<<256, 1024, 0, stream>>>(seqp, Wp, bp, hcat);
    out_gemm<<<1280, 512, 0, stream>>>(hcat, W3p, out_b, out);
}

// Round 6
// 511.246 us; speedup vs baseline: 1.4195x; 1.4195x over previous
//
#include <hip/hip_runtime.h>
#include <hip/hip_fp16.h>

typedef _Float16 f16;
typedef _Float16 f16x2 __attribute__((ext_vector_type(2)));
typedef _Float16 f16x8 __attribute__((ext_vector_type(8)));
typedef float    f32x4 __attribute__((ext_vector_type(4)));

#define NB   8192
#define TOUT 10
#define LMAX 12
#define EMB  300

__device__ __forceinline__ float sigm_(float x) {
    return __builtin_amdgcn_rcpf(1.0f + __builtin_amdgcn_exp2f(x * -1.44269504f));
}
__device__ __forceinline__ float tanh_(float x) {
    return 1.0f - 2.0f * __builtin_amdgcn_rcpf(1.0f + __builtin_amdgcn_exp2f(x * 2.88539008f));
}

// async global->LDS, 16B per lane. LDS dest is wave-uniform base + lane*16.
// NOTE (round-5 lesson): gl_lds reads do NOT re-hit L2 like VGPR loads --
// use ONLY for true HBM streams (seq), never for L2-resident data (weights).
__device__ __forceinline__ void gl_lds16(const f16* g, f16* l) {
    __builtin_amdgcn_global_load_lds(
        (const __attribute__((address_space(1))) void*)g,
        (__attribute__((address_space(3))) void*)l, 16, 0, 0);
}

// ---------------------------------------------------------------------------
// K0a: pack LSTM weights into MFMA B-fragment tiles, f16, gate-permuted cols.
// Dest per dir: [kc 0..15][ntile 0..63][512 f16]; within tile element (k,n):
// offset = ((k%32)/8*16 + n%16)*8 + k%8 (lane l reads l*8..l*8+7).
// 16-wave / 64-col-per-wave permutation, PASS-ORDERED gates:
//   tile-local gate slot g' = (n>>4)&3 maps to source gate
//   sg = ((g'&1)<<1)|(g'>>1)  ->  order (i, g, f, o)
// so pass A (nt 0,1) = gates i,g and pass B (nt 2,3) = gates f,o.
// unit u = ((n>>6)<<4) | (n&15); lane l16 owns unit wave*16+l16.
// ---------------------------------------------------------------------------
__global__ __launch_bounds__(256) void pack_w2(
    const float* __restrict__ wih_f, const float* __restrict__ whh_f,
    const float* __restrict__ wih_b, const float* __restrict__ whh_b,
    f16* __restrict__ Wp) {
    int idx = blockIdx.x * 256 + threadIdx.x;   // 0 .. 2*524288-1
    int d   = idx >> 19;
    int r   = idx & 524287;
    int tile = r >> 9;
    int e    = r & 511;
    int kc = tile >> 6, nt = tile & 63;
    int khi = e >> 7, rem = e & 127, nl = rem >> 3, klo = rem & 7;
    int n = nt * 16 + nl;
    int k = kc * 32 + khi * 8 + klo;
    int gp = (n >> 4) & 3;
    int sg = ((gp & 1) << 1) | (gp >> 1);       // i,g,f,o order
    int u = ((n >> 6) << 4) | (n & 15);
    int srow = sg * 256 + u;
    const float* wih = d ? wih_b : wih_f;
    const float* whh = d ? whh_b : whh_f;
    float v = (k < 256) ? wih[srow * 256 + k] : whh[srow * 256 + (k - 256)];
    Wp[idx] = (f16)v;
}

__global__ __launch_bounds__(256) void pack_bias(
    const float* __restrict__ bih_f, const float* __restrict__ bhh_f,
    const float* __restrict__ bih_b, const float* __restrict__ bhh_b,
    float* __restrict__ bp) {
    int idx = blockIdx.x * 256 + threadIdx.x;   // 2048
    int d = idx >> 10, n = idx & 1023;
    int gp = (n >> 4) & 3;
    int sg = ((gp & 1) << 1) | (gp >> 1);
    int u = ((n >> 6) << 4) | (n & 15);
    int srow = sg * 256 + u;
    bp[idx] = d ? (bih_b[srow] + bhh_b[srow]) : (bih_f[srow] + bhh_f[srow]);
}

// K0b: pack out_w (512x512) into B-fragment tiles: [kc 0..15][ntile 0..31][512]
__global__ __launch_bounds__(256) void pack_w3(
    const float* __restrict__ out_w, f16* __restrict__ W3p) {
    int idx = blockIdx.x * 256 + threadIdx.x;   // 262144
    int tile = idx >> 9, e = idx & 511;
    int kc = tile >> 5, nt = tile & 31;
    int khi = e >> 7, rem = e & 127, nl = rem >> 3, klo = rem & 7;
    int n = nt * 16 + nl, k = kc * 32 + khi * 8 + klo;
    W3p[idx] = (f16)out_w[n * 512 + k];
}

// K0c: P[36][256] = emb_table @ enc_w^T + enc_b (fp32)
__global__ __launch_bounds__(256) void enc_proj(
    const float* __restrict__ tab, const float* __restrict__ ew,
    const float* __restrict__ eb, float* __restrict__ P) {
    int v = blockIdx.x, j = threadIdx.x;
    const float* a = tab + v * EMB;
    const float* w = ew + j * EMB;
    float s = 0.0f;
    for (int k = 0; k < EMB; ++k) s += a[k] * w[k];
    P[v * 256 + j] = s + eb[j];
}

// ---------------------------------------------------------------------------
// K1: build seq in MFMA A-fragment tile layout, f16.
// seqp: [t 0..9][mtile 0..511][kc 0..7][512 f16]; element (row,k):
// offset = ((k%32)/8*16 + row%16)*8 + k%8
// ---------------------------------------------------------------------------
__global__ __launch_bounds__(256) void build_seq(
    const int* __restrict__ words, const int* __restrict__ lengths,
    const float* __restrict__ P, f16* __restrict__ seqp) {
    int gi = blockIdx.x * 256 + threadIdx.x;    // 2,621,440 total
    int bl  = gi & 15;
    int khi = (gi >> 4) & 3;
    int kc  = (gi >> 6) & 7;
    int mt  = (gi >> 9) & 511;
    int t   = gi >> 18;
    int b = mt * 16 + bl;
    int L = lengths[b];
    float pos = ((float)t * (float)(L - 1)) / 9.0f;
    int i0 = (int)pos;
    float f = pos - (float)i0;
    int i1 = min(i0 + 1, L - 1);
    int c0 = words[b * LMAX + i0];
    int c1 = words[b * LMAX + i1];
    const float* p0 = P + c0 * 256 + kc * 32 + khi * 8;
    const float* p1 = P + c1 * 256 + kc * 32 + khi * 8;
    f16x8 r;
#pragma unroll
    for (int j = 0; j < 8; ++j) {
        float v = p0[j] * (1.0f - f) + p1[j] * f;
        v = fmaxf(v, 0.0f);
        r[j] = (f16)v;
    }
    *((f16x8*)seqp + gi) = r;
}

// ---------------------------------------------------------------------------
// K2: fused BiLSTM. 256 blocks x 1024 thr (16 waves), 1 block/CU, 4 w/SIMD.
// Round-6: TWO COLUMN-PASSES per step. Pass A computes gates (i,g) only
// (acc[4][2] = 32 AGPR, half of before) and collapses to z = sig(i)*tanh(g)
// (16 regs); pass B computes (f,o) and finishes the cell. The freed ~32
// VGPRs hold a bE/bO weight-fragment rotation: chunk k's MFMA overlaps
// chunk k+1's 2 global loads (plain VGPR loads -> L2-resident; round-5's
// gl_lds weight streaming bypassed L2, FETCH 929 MB). During the K-loop
// the vmcnt FIFO contains ONLY weight loads, so the compiler's counted
// waits are tight; the seq DMA is issued at the FIFO TAIL (after the last
// weight load) and drained by the step barrier, never by a counted wait.
// LDS = hbuf dbuf 64 KB + sbuf dbuf 64 KB. One barrier per step.
// ---------------------------------------------------------------------------
__global__ __launch_bounds__(1024) void lstm_fused(
    const f16* __restrict__ seqp, const f16* __restrict__ Wp,
    const float* __restrict__ bp, f16* __restrict__ hcat) {
    const int dir  = blockIdx.x >> 7;
    const int r0t  = (blockIdx.x & 127) << 2;   // row-tile base, 4 tiles of 16
    const int wave = threadIdx.x >> 6;          // 0..15
    const int lane = threadIdx.x & 63;
    const int l16  = lane & 15;
    const int quad = lane >> 4;

    __shared__ __align__(16) f16 hbuf[2][16384];   // 2 x 32 KB h state
    __shared__ __align__(16) f16 sbuf[2][16384];   // 2 x 32 KB seq tiles

    // zero h0
    {
        f16x8 z = {(f16)0, (f16)0, (f16)0, (f16)0, (f16)0, (f16)0, (f16)0, (f16)0};
        for (int i = threadIdx.x; i < 2048; i += 1024) ((f16x8*)hbuf[0])[i] = z;
    }
    // stage seq tile for t0
    {
        const int t0 = dir ? 9 : 0;
        const f16* s0 = seqp + (size_t)(t0 * 512 + r0t) * 4096;
        gl_lds16(s0 + threadIdx.x * 8,        &sbuf[0][wave * 512]);
        gl_lds16(s0 + 8192 + threadIdx.x * 8, &sbuf[0][8192 + wave * 512]);
    }

    // per-lane gate biases (pass-ordered: 0=i, 1=g, 2=f, 3=o)
    const float* bpd = bp + dir * 1024 + wave * 64;
    float bias_l[4];
#pragma unroll
    for (int nt = 0; nt < 4; ++nt) bias_l[nt] = bpd[nt * 16 + l16];

    // weight tile (kc, ntl): Wsl + kc*32768 + ntl*512
    const f16* Wsl = Wp + dir * 524288 + wave * 2048 + lane * 8;

    // combine geometry: lane owns h-unit u = wave*16 + l16
    const int slot = wave >> 1;
    const int ofs0 = (((wave & 1) * 2 + (l16 >> 3)) * 16 + quad * 4) * 8 + (l16 & 7);
    const int tile_lo = (r0t * 16 + dir * 8 + slot) * 512;

    float cst[4][4];
#pragma unroll
    for (int m = 0; m < 4; ++m)
#pragma unroll
        for (int q = 0; q < 4; ++q) cst[m][q] = 0.0f;

    __syncthreads();   // drains h0 zero + t0 seq DMA

// K-loop over 16 chunks with bE/bO depth-1 weight rotation.
// PB = 0 (pass A: i,g) or 2 (pass B: f,o).
#define KLOOP(PB, acc)                                                         \
    {                                                                          \
        f16x8 bE0 = *(const f16x8*)(Wsl + (PB) * 512);                         \
        f16x8 bE1 = *(const f16x8*)(Wsl + ((PB) + 1) * 512);                   \
        f16x8 bO0 = *(const f16x8*)(Wsl + 32768 + (PB) * 512);                 \
        f16x8 bO1 = *(const f16x8*)(Wsl + 32768 + ((PB) + 1) * 512);           \
        _Pragma("unroll 1")                                                    \
        for (int k2 = 0; k2 < 8; ++k2) {                                       \
            const f16* ab = (k2 < 4) ? sbl : hbl;                              \
            const int ke = (2 * k2) & 7, ko = (2 * k2 + 1) & 7;                \
            f16x8 a0 = *(const f16x8*)(ab + (0 * 8 + ke) * 512);               \
            f16x8 a1 = *(const f16x8*)(ab + (1 * 8 + ke) * 512);               \
            f16x8 a2 = *(const f16x8*)(ab + (2 * 8 + ke) * 512);               \
            f16x8 a3 = *(const f16x8*)(ab + (3 * 8 + ke) * 512);               \
            __builtin_amdgcn_s_setprio(1);                                     \
            acc[0][0] = __builtin_amdgcn_mfma_f32_16x16x32_f16(a0, bE0, acc[0][0], 0, 0, 0); \
            acc[1][0] = __builtin_amdgcn_mfma_f32_16x16x32_f16(a1, bE0, acc[1][0], 0, 0, 0); \
            acc[2][0] = __builtin_amdgcn_mfma_f32_16x16x32_f16(a2, bE0, acc[2][0], 0, 0, 0); \
            acc[3][0] = __builtin_amdgcn_mfma_f32_16x16x32_f16(a3, bE0, acc[3][0], 0, 0, 0); \
            acc[0][1] = __builtin_amdgcn_mfma_f32_16x16x32_f16(a0, bE1, acc[0][1], 0, 0, 0); \
            acc[1][1] = __builtin_amdgcn_mfma_f32_16x16x32_f16(a1, bE1, acc[1][1], 0, 0, 0); \
            acc[2][1] = __builtin_amdgcn_mfma_f32_16x16x32_f16(a2, bE1, acc[2][1], 0, 0, 0); \
            acc[3][1] = __builtin_amdgcn_mfma_f32_16x16x32_f16(a3, bE1, acc[3][1], 0, 0, 0); \
            __builtin_amdgcn_s_setprio(0);                                     \
            if (k2 < 7) {   /* prefetch even chunk k+2 into dead bE regs */    \
                const f16* wn = Wsl + (2 * k2 + 2) * 32768;                    \
                bE0 = *(const f16x8*)(wn + (PB) * 512);                        \
                bE1 = *(const f16x8*)(wn + ((PB) + 1) * 512);                  \
            }                                                                  \
            a0 = *(const f16x8*)(ab + (0 * 8 + ko) * 512);                     \
            a1 = *(const f16x8*)(ab + (1 * 8 + ko) * 512);                     \
            a2 = *(const f16x8*)(ab + (2 * 8 + ko) * 512);                     \
            a3 = *(const f16x8*)(ab + (3 * 8 + ko) * 512);                     \
            __builtin_amdgcn_s_setprio(1);                                     \
            acc[0][0] = __builtin_amdgcn_mfma_f32_16x16x32_f16(a0, bO0, acc[0][0], 0, 0, 0); \
            acc[1][0] = __builtin_amdgcn_mfma_f32_16x16x32_f16(a1, bO0, acc[1][0], 0, 0, 0); \
            acc[2][0] = __builtin_amdgcn_mfma_f32_16x16x32_f16(a2, bO0, acc[2][0], 0, 0, 0); \
            acc[3][0] = __builtin_amdgcn_mfma_f32_16x16x32_f16(a3, bO0, acc[3][0], 0, 0, 0); \
            acc[0][1] = __builtin_amdgcn_mfma_f32_16x16x32_f16(a0, bO1, acc[0][1], 0, 0, 0); \
            acc[1][1] = __builtin_amdgcn_mfma_f32_16x16x32_f16(a1, bO1, acc[1][1], 0, 0, 0); \
            acc[2][1] = __builtin_amdgcn_mfma_f32_16x16x32_f16(a2, bO1, acc[2][1], 0, 0, 0); \
            acc[3][1] = __builtin_amdgcn_mfma_f32_16x16x32_f16(a3, bO1, acc[3][1], 0, 0, 0); \
            __builtin_amdgcn_s_setprio(0);                                     \
            if (k2 < 7) {   /* prefetch odd chunk k+2 into dead bO regs */     \
                const f16* wn = Wsl + (2 * k2 + 3) * 32768;                    \
                bO0 = *(const f16x8*)(wn + (PB) * 512);                        \
                bO1 = *(const f16x8*)(wn + ((PB) + 1) * 512);                  \
            }                                                                  \
        }                                                                      \
    }

    int cur = 0;
#pragma unroll 1
    for (int step = 0; step < TOUT; ++step) {
        const int t = dir ? (9 - step) : step;
        const f16* sbl = sbuf[cur] + lane * 8;
        const f16* hbl = hbuf[cur] + lane * 8;
        f16*       hb_w = hbuf[cur ^ 1];

        // ---- pass A: gates i,g -> z ----
        float z[4][4];
        {
            f32x4 acc[4][2];
#pragma unroll
            for (int m = 0; m < 4; ++m)
#pragma unroll
                for (int q = 0; q < 4; ++q) { acc[m][0][q] = bias_l[0]; acc[m][1][q] = bias_l[1]; }
            KLOOP(0, acc);
#pragma unroll
            for (int m = 0; m < 4; ++m)
#pragma unroll
                for (int q = 0; q < 4; ++q)
                    z[m][q] = sigm_(acc[m][0][q]) * tanh_(acc[m][1][q]);
        }

        // ---- pass B: gates f,o -> cell update ----
        {
            f32x4 acc[4][2];
#pragma unroll
            for (int m = 0; m < 4; ++m)
#pragma unroll
                for (int q = 0; q < 4; ++q) { acc[m][0][q] = bias_l[2]; acc[m][1][q] = bias_l[3]; }
            KLOOP(2, acc);

            // seq prefetch for next step: FIFO TAIL (after all weight loads),
            // drained by the step barrier -- never by a counted wait.
            if (step != 9) {
                const int tn = dir ? (t - 1) : (t + 1);
                const f16* ns = seqp + (size_t)(tn * 512 + r0t) * 4096;
                gl_lds16(ns + threadIdx.x * 8,        &sbuf[cur ^ 1][wave * 512]);
                gl_lds16(ns + 8192 + threadIdx.x * 8, &sbuf[cur ^ 1][8192 + wave * 512]);
            }

            // combine; h -> LDS (recurrence) + global hcat (scatter f16)
            f16* hct = hcat + ((size_t)t * 4194304 + tile_lo);
#pragma unroll
            for (int m = 0; m < 4; ++m) {
#pragma unroll
                for (int q = 0; q < 4; ++q) {
                    float c = sigm_(acc[m][0][q]) * cst[m][q] + z[m][q];
                    cst[m][q] = c;
                    f16 hv = (f16)(sigm_(acc[m][1][q]) * tanh_(c));
                    int wt = ofs0 + q * 8;
                    hb_w[(m * 8 + slot) * 512 + wt] = hv;
                    hct[m * 8192 + wt] = hv;
                }
            }
        }

        __syncthreads();   // single barrier per step; drains seq DMA + stores
        cur ^= 1;
    }
#undef KLOOP
}

// ---------------------------------------------------------------------------
// K3: out = h_cat(81920x512 f16, frag layout) @ W3p + out_b -> fp32 (B,10,512)
// 1280 blocks x 512 thr; block tile 64 rows x 512 cols; wave: 64x64.
// ---------------------------------------------------------------------------
__global__ __launch_bounds__(512) void out_gemm(
    const f16* __restrict__ hcat, const f16* __restrict__ W3p,
    const float* __restrict__ out_b, float* __restrict__ out) {
    const int mt0  = blockIdx.x << 2;
    const int wave = threadIdx.x >> 6;
    const int lane = threadIdx.x & 63;
    const int l16  = lane & 15;
    const int quad = lane >> 4;
    const int n0   = wave * 64;

    float bias_l[4];
#pragma unroll
    for (int nt = 0; nt < 4; ++nt) bias_l[nt] = out_b[n0 + nt * 16 + l16];

    f32x4 acc[4][4];
#pragma unroll
    for (int m = 0; m < 4; ++m)
#pragma unroll
        for (int nt = 0; nt < 4; ++nt)
#pragma unroll
            for (int q = 0; q < 4; ++q) acc[m][nt][q] = bias_l[nt];

#pragma unroll 2
    for (int kc = 0; kc < 16; ++kc) {
        f16x8 a[4], b[4];
#pragma unroll
        for (int m = 0; m < 4; ++m)
            a[m] = *(const f16x8*)(hcat + ((size_t)((mt0 + m) * 16 + kc) * 512 + lane * 8));
#pragma unroll
        for (int nt = 0; nt < 4; ++nt)
            b[nt] = *(const f16x8*)(W3p + ((kc * 32 + wave * 4 + nt) * 512 + lane * 8));
#pragma unroll
        for (int m = 0; m < 4; ++m)
#pragma unroll
            for (int nt = 0; nt < 4; ++nt)
                acc[m][nt] = __builtin_amdgcn_mfma_f32_16x16x32_f16(a[m], b[nt], acc[m][nt], 0, 0, 0);
    }

#pragma unroll
    for (int m = 0; m < 4; ++m) {
#pragma unroll
        for (int nt = 0; nt < 4; ++nt) {
#pragma unroll
            for (int q = 0; q < 4; ++q) {
                int R = mt0 * 16 + m * 16 + quad * 4 + q;
                int t = R >> 13;
                int b = R & 8191;
                out[(size_t)(b * 10 + t) * 512 + n0 + nt * 16 + l16] = acc[m][nt][q];
            }
        }
    }
}

// ---------------------------------------------------------------------------
extern "C" void kernel_launch(void* const* d_in, const int* in_sizes, int n_in,
                              void* d_out, int out_size, void* d_ws, size_t ws_size,
                              hipStream_t stream) {
    const int*   words   = (const int*)d_in[0];
    const int*   lengths = (const int*)d_in[1];
    const float* tab     = (const float*)d_in[2];
    const float* enc_w   = (const float*)d_in[3];
    const float* enc_b   = (const float*)d_in[4];
    const float* wih_f   = (const float*)d_in[5];
    const float* whh_f   = (const float*)d_in[6];
    const float* bih_f   = (const float*)d_in[7];
    const float* bhh_f   = (const float*)d_in[8];
    const float* wih_b   = (const float*)d_in[9];
    const float* whh_b   = (const float*)d_in[10];
    const float* bih_b   = (const float*)d_in[11];
    const float* bhh_b   = (const float*)d_in[12];
    const float* out_w   = (const float*)d_in[13];
    const float* out_b   = (const float*)d_in[14];
    float* out = (float*)d_out;

    char* ws = (char*)d_ws;
    f16*   Wp   = (f16*)(ws + 0);           //  2 MB
    f16*   W3p  = (f16*)(ws + 2097152);     //  0.5 MB
    float* bp   = (float*)(ws + 2621440);   //  8 KB
    float* P    = (float*)(ws + 2629632);   //  36 KB
    f16*   seqp = (f16*)(ws + 2666496);     //  40 MB
    f16*   hcat = (f16*)(ws + 44609536);    //  80 MB  (total ~122.6 MB)

    pack_w2<<<4096, 256, 0, stream>>>(wih_f, whh_f, wih_b, whh_b, Wp);
    pack_bias<<<8, 256, 0, stream>>>(bih_f, bhh_f, bih_b, bhh_b, bp);
    pack_w3<<<1024, 256, 0, stream>>>(out_w, W3p);
    enc_proj<<<36, 256, 0, stream>>>(tab, enc_w, enc_b, P);
    build_seq<<<10240, 256, 0, stream>>>(words, lengths, P, seqp);
    lstm_fused<<<256, 1024, 0, stream>>>(seqp, Wp, bp, hcat);
    out_gemm<<<1280, 512, 0, stream>>>(hcat, W3p, out_b, out);
}